// Round 1
// baseline (233.207 us; speedup 1.0000x reference)
//
#include <hip/hip_runtime.h>
#include <math.h>

#define NROW 16384          // B*S
#define SCALE 0.2886751345948129f   // 1/sqrt(12)

// ---------------- Kernel 1: QKV projection ----------------
// grid = 256 row-groups * 3 mats = 768 blocks, block = 128 threads (2 waves).
// Each block: 64 rows, one of {q,k,v}. Waves split D; x staged via LDS for
// coalescing; weight loads wave-uniform -> scalar loads.
__global__ __launch_bounds__(128)
void qkv_proj(const float* __restrict__ x,
              const float* __restrict__ Wq,
              const float* __restrict__ Wk,
              const float* __restrict__ Wv,
              float* __restrict__ qout,
              float* __restrict__ kout,
              float* __restrict__ vout)
{
    __shared__ float xs[2][64][65];   // pad 65: conflict-free both phases
    __shared__ float pacc[64][12];

    const int tid  = threadIdx.x;
    const int lane = tid & 63;
    const int w    = tid >> 6;        // 0 or 1
    const int rg   = blockIdx.x / 3;
    const int mat  = blockIdx.x % 3;
    const int base = rg * 64;

    const float* __restrict__ W   = (mat == 0) ? Wq  : (mat == 1) ? Wk  : Wv;
    float*       __restrict__ out = (mat == 0) ? qout : (mat == 1) ? kout : vout;

    float acc[12];
    #pragma unroll
    for (int h = 0; h < 12; ++h) acc[h] = 0.f;

    // wave w handles d-chunks d0 = c*128 + w*64, c = 0..5 (private LDS buffer,
    // same-wave RAW through LDS -> no __syncthreads needed inside the loop)
    for (int c = 0; c < 6; ++c) {
        const int d0 = c * 128 + w * 64;
        #pragma unroll
        for (int i = 0; i < 16; ++i) {
            int idx = i * 64 + lane;
            int r   = idx >> 4;
            int c4  = (idx & 15) << 2;
            float4 v = *(const float4*)(x + (size_t)(base + r) * 768 + d0 + c4);
            xs[w][r][c4 + 0] = v.x;
            xs[w][r][c4 + 1] = v.y;
            xs[w][r][c4 + 2] = v.z;
            xs[w][r][c4 + 3] = v.w;
        }
        #pragma unroll 4
        for (int dd = 0; dd < 64; ++dd) {
            float xv = xs[w][lane][dd];
            const float* wr = W + (size_t)(d0 + dd) * 12;   // wave-uniform
            #pragma unroll
            for (int h = 0; h < 12; ++h) acc[h] = fmaf(xv, wr[h], acc[h]);
        }
    }

    if (w == 1) {
        #pragma unroll
        for (int h = 0; h < 12; ++h) pacc[lane][h] = acc[h];
    }
    __syncthreads();
    if (w == 0) {
        #pragma unroll
        for (int h = 0; h < 12; ++h) acc[h] += pacc[lane][h];
        float4* op = (float4*)(out + (size_t)(base + lane) * 12);
        op[0] = make_float4(acc[0], acc[1], acc[2],  acc[3]);
        op[1] = make_float4(acc[4], acc[5], acc[6],  acc[7]);
        op[2] = make_float4(acc[8], acc[9], acc[10], acc[11]);
    }
}

// ---------------- Kernel 2: flash attention (fp32, H=12) ----------------
// grid = 8 batches * 32 row-groups = 256 blocks, block = 512 threads (8 waves).
// lane <-> query row (64 rows/block); waves split the 2048 keys (256 each),
// per-lane online softmax; k/v/mask reads are wave-uniform -> scalar loads;
// masked keys skipped by a uniform scalar branch. LDS combine at the end.
__global__ __launch_bounds__(512)
void attn(const float* __restrict__ q_ws,
          const float* __restrict__ k_ws,
          const float* __restrict__ v_ws,
          const int*   __restrict__ mask,
          float*       __restrict__ out)
{
    __shared__ float rm[8][64];
    __shared__ float rl[8][64];
    __shared__ float ro[8][64][12];

    const int tid  = threadIdx.x;
    const int lane = tid & 63;
    const int w    = __builtin_amdgcn_readfirstlane(tid >> 6);  // force SGPR
    const int bb   = blockIdx.x >> 5;   // batch
    const int rg   = blockIdx.x & 31;   // row group
    const int grow = bb * 2048 + rg * 64 + lane;

    float q[12];
    {
        const float4* qp = (const float4*)(q_ws + (size_t)grow * 12);
        float4 a = qp[0], b = qp[1], c = qp[2];
        q[0]=a.x; q[1]=a.y; q[2]=a.z;  q[3]=a.w;
        q[4]=b.x; q[5]=b.y; q[6]=b.z;  q[7]=b.w;
        q[8]=c.x; q[9]=c.y; q[10]=c.z; q[11]=c.w;
    }

    const float* kb = k_ws + (size_t)bb * 2048 * 12;
    const float* vb = v_ws + (size_t)bb * 2048 * 12;
    const int*   mb = mask + bb * 2048;

    float m = -INFINITY, l = 0.f;
    float o[12];
    #pragma unroll
    for (int j = 0; j < 12; ++j) o[j] = 0.f;

    const int t0 = w * 256;
    for (int tt = t0; tt < t0 + 256; ++tt) {
        if (mb[tt] == 0) continue;              // wave-uniform branch
        const float* kr = kb + (size_t)tt * 12; // wave-uniform -> s_load
        // dot product as a tree (latency)
        float s0 = q[0] * kr[0];
        float s1 = q[1] * kr[1];
        float s2 = q[2] * kr[2];
        float s3 = q[3] * kr[3];
        s0 = fmaf(q[4], kr[4], s0);
        s1 = fmaf(q[5], kr[5], s1);
        s2 = fmaf(q[6], kr[6], s2);
        s3 = fmaf(q[7], kr[7], s3);
        s0 = fmaf(q[8], kr[8], s0);
        s1 = fmaf(q[9], kr[9], s1);
        s2 = fmaf(q[10], kr[10], s2);
        s3 = fmaf(q[11], kr[11], s3);
        float s = ((s0 + s1) + (s2 + s3)) * SCALE;

        const float* vr = vb + (size_t)tt * 12; // wave-uniform -> s_load
        if (s <= m) {
            float p = __expf(s - m);
            l += p;
            #pragma unroll
            for (int j = 0; j < 12; ++j) o[j] = fmaf(p, vr[j], o[j]);
        } else {
            float a = __expf(m - s);            // p(new max) == 1
            l = fmaf(l, a, 1.f);
            #pragma unroll
            for (int j = 0; j < 12; ++j) o[j] = fmaf(o[j], a, vr[j]);
            m = s;
        }
    }

    rm[w][lane] = m;
    rl[w][lane] = l;
    #pragma unroll
    for (int j = 0; j < 12; ++j) ro[w][lane][j] = o[j];
    __syncthreads();

    if (tid < 64) {
        float gm = rm[0][tid];
        #pragma unroll
        for (int w2 = 1; w2 < 8; ++w2) gm = fmaxf(gm, rm[w2][tid]);
        float L = 0.f;
        float O[12];
        #pragma unroll
        for (int j = 0; j < 12; ++j) O[j] = 0.f;
        #pragma unroll
        for (int w2 = 0; w2 < 8; ++w2) {
            float a = __expf(rm[w2][tid] - gm);
            L = fmaf(rl[w2][tid], a, L);
            #pragma unroll
            for (int j = 0; j < 12; ++j) O[j] = fmaf(ro[w2][tid][j], a, O[j]);
        }
        float inv = 1.f / L;
        float* op = out + ((size_t)blockIdx.x * 64 + tid) * 12;
        #pragma unroll
        for (int j = 0; j < 12; ++j) op[j] = O[j] * inv;
    }
}

extern "C" void kernel_launch(void* const* d_in, const int* in_sizes, int n_in,
                              void* d_out, int out_size, void* d_ws, size_t ws_size,
                              hipStream_t stream) {
    const float* x    = (const float*)d_in[0];
    const int*   mask = (const int*)  d_in[1];
    const float* Wk   = (const float*)d_in[2];   // key_weight
    const float* Wq   = (const float*)d_in[3];   // query_weight
    const float* Wv   = (const float*)d_in[4];   // value_weight
    float* out = (float*)d_out;

    float* ws   = (float*)d_ws;
    float* q_ws = ws;
    float* k_ws = ws + NROW * 12;       // 196608 floats each
    float* v_ws = ws + 2 * NROW * 12;

    qkv_proj<<<768, 128, 0, stream>>>(x, Wq, Wk, Wv, q_ws, k_ws, v_ws);
    attn<<<256, 512, 0, stream>>>(q_ws, k_ws, v_ws, mask, out);
}

// Round 2
// 136.026 us; speedup vs baseline: 1.7144x; 1.7144x over previous
//
#include <hip/hip_runtime.h>
#include <math.h>

#define QSCALE (0.2886751345948129f * 1.4426950408889634f)  // 1/sqrt(12) * log2(e)

#if __has_builtin(__builtin_amdgcn_exp2f)
#define EXP2F(x) __builtin_amdgcn_exp2f(x)
#else
#define EXP2F(x) exp2f(x)
#endif

// ---------------- Kernel 0: mask scan / compaction indices ----------------
// One block per batch. dst[b][t] = compacted index (or -1), nvalid[b] = count.
__global__ __launch_bounds__(256)
void mask_scan(const int* __restrict__ mask, int* __restrict__ dst,
               int* __restrict__ nvalid)
{
    __shared__ int cnt[256];
    const int b = blockIdx.x;
    const int t = threadIdx.x;
    const int* mb = mask + b * 2048;
    int local[8]; int c = 0;
    #pragma unroll
    for (int i = 0; i < 8; ++i) { local[i] = (mb[t * 8 + i] != 0); c += local[i]; }
    cnt[t] = c;
    __syncthreads();
    for (int off = 1; off < 256; off <<= 1) {
        int u = cnt[t];
        int add = (t >= off) ? cnt[t - off] : 0;
        __syncthreads();
        cnt[t] = u + add;
        __syncthreads();
    }
    int run = (t == 0) ? 0 : cnt[t - 1];
    int* db = dst + b * 2048;
    #pragma unroll
    for (int i = 0; i < 8; ++i) { db[t * 8 + i] = local[i] ? run : -1; run += local[i]; }
    if (t == 255) nvalid[b] = cnt[255];
}

// ---------------- Kernel 1: QKV projection (fused, compacted k/v out) ------
// grid=256 blocks (64 rows each), block=512 (8 waves). Waves split D into
// 48 chunks of 16; per-wave private LDS x-tile (pad 17, conflict-free),
// register prefetch of next chunk; weights via wave-uniform scalar loads.
// q written pre-scaled by 1/sqrt(12)*log2e; k/v written compacted via dst.
__global__ __launch_bounds__(512)
void qkv_proj(const float* __restrict__ x, const float* __restrict__ Wq,
              const float* __restrict__ Wk, const float* __restrict__ Wv,
              const int* __restrict__ dst, float* __restrict__ q_ws,
              float* __restrict__ kc, float* __restrict__ vc)
{
    __shared__ float smem[9216];   // phase A: xs[8][64][17]; phase B: pacc[4][64][36]
    const int tid  = threadIdx.x;
    const int lane = tid & 63;
    const int w    = tid >> 6;
    const int base = blockIdx.x * 64;
    float* xw = smem + w * 1088;   // 64*17 floats per wave

    float acc[36];
    #pragma unroll
    for (int j = 0; j < 36; ++j) acc[j] = 0.f;

    float4 pf[4];
    {
        const int d0 = w * 16;
        #pragma unroll
        for (int i = 0; i < 4; ++i) {
            int idx = i * 64 + lane;
            int r = idx >> 2, c4 = (idx & 3) << 2;
            pf[i] = *(const float4*)(x + (size_t)(base + r) * 768 + d0 + c4);
        }
    }

    #pragma unroll
    for (int k = 0; k < 6; ++k) {
        // write current prefetched chunk to LDS (same-wave, DS ops in-order)
        #pragma unroll
        for (int i = 0; i < 4; ++i) {
            int idx = i * 64 + lane;
            int r = idx >> 2, c4 = (idx & 3) << 2;
            float* p = xw + r * 17 + c4;
            p[0] = pf[i].x; p[1] = pf[i].y; p[2] = pf[i].z; p[3] = pf[i].w;
        }
        // issue next chunk's global loads (in flight during compute)
        if (k < 5) {
            const int d0n = (w + (k + 1) * 8) * 16;
            #pragma unroll
            for (int i = 0; i < 4; ++i) {
                int idx = i * 64 + lane;
                int r = idx >> 2, c4 = (idx & 3) << 2;
                pf[i] = *(const float4*)(x + (size_t)(base + r) * 768 + d0n + c4);
            }
        }
        const int d0u = __builtin_amdgcn_readfirstlane((w + k * 8) * 16);
        #pragma unroll 4
        for (int dd = 0; dd < 16; ++dd) {
            float xv = xw[lane * 17 + dd];
            const float* wq = Wq + (d0u + dd) * 12;   // wave-uniform -> s_load
            const float* wk = Wk + (d0u + dd) * 12;
            const float* wv = Wv + (d0u + dd) * 12;
            #pragma unroll
            for (int h = 0; h < 12; ++h) acc[h]      = fmaf(xv, wq[h], acc[h]);
            #pragma unroll
            for (int h = 0; h < 12; ++h) acc[12 + h] = fmaf(xv, wk[h], acc[12 + h]);
            #pragma unroll
            for (int h = 0; h < 12; ++h) acc[24 + h] = fmaf(xv, wv[h], acc[24 + h]);
        }
    }

    // ---- cross-wave tree combine (aliases the xs region; sync first) ----
    float* pacc = smem;   // [4][64][36]
    __syncthreads();
    if (w >= 4) {
        float* p = pacc + ((w - 4) * 64 + lane) * 36;
        #pragma unroll
        for (int j = 0; j < 36; ++j) p[j] = acc[j];
    }
    __syncthreads();
    if (w < 4) {
        const float* p = pacc + (w * 64 + lane) * 36;
        #pragma unroll
        for (int j = 0; j < 36; ++j) acc[j] += p[j];
    }
    __syncthreads();
    if (w == 2 || w == 3) {
        float* p = pacc + ((w - 2) * 64 + lane) * 36;
        #pragma unroll
        for (int j = 0; j < 36; ++j) p[j] = acc[j];
    }
    __syncthreads();
    if (w < 2) {
        const float* p = pacc + (w * 64 + lane) * 36;
        #pragma unroll
        for (int j = 0; j < 36; ++j) acc[j] += p[j];
    }
    __syncthreads();
    if (w == 1) {
        float* p = pacc + lane * 36;
        #pragma unroll
        for (int j = 0; j < 36; ++j) p[j] = acc[j];
    }
    __syncthreads();
    if (w == 0) {
        const float* p = pacc + lane * 36;
        #pragma unroll
        for (int j = 0; j < 36; ++j) acc[j] += p[j];

        const int row = base + lane;
        float4* qp = (float4*)(q_ws + (size_t)row * 12);
        qp[0] = make_float4(acc[0] * QSCALE, acc[1] * QSCALE, acc[2] * QSCALE, acc[3] * QSCALE);
        qp[1] = make_float4(acc[4] * QSCALE, acc[5] * QSCALE, acc[6] * QSCALE, acc[7] * QSCALE);
        qp[2] = make_float4(acc[8] * QSCALE, acc[9] * QSCALE, acc[10] * QSCALE, acc[11] * QSCALE);

        const int d = dst[row];
        if (d >= 0) {
            const int b = row >> 11;
            float4* kp = (float4*)(kc + (size_t)(b * 2048 + d) * 12);
            kp[0] = make_float4(acc[12], acc[13], acc[14], acc[15]);
            kp[1] = make_float4(acc[16], acc[17], acc[18], acc[19]);
            kp[2] = make_float4(acc[20], acc[21], acc[22], acc[23]);
            float4* vp = (float4*)(vc + (size_t)(b * 2048 + d) * 12);
            vp[0] = make_float4(acc[24], acc[25], acc[26], acc[27]);
            vp[1] = make_float4(acc[28], acc[29], acc[30], acc[31]);
            vp[2] = make_float4(acc[32], acc[33], acc[34], acc[35]);
        }
    }
}

// ---------------- Kernel 2: flash attention over compacted keys ------------
// grid = 8 batches * 32 rowgroups = 256 blocks, block = 1024 (16 waves).
// lane <-> query row; waves take 16-key slices of each 256-key LDS tile
// (double-buffered, register-prefetched). Two-pass-per-tile softmax in exp2
// domain, s[16] kept in registers. 16-way LDS combine at the end.
__global__ __launch_bounds__(1024)
void attn(const float* __restrict__ q_ws, const float* __restrict__ kc,
          const float* __restrict__ vc, const int* __restrict__ nvalid_arr,
          float* __restrict__ out)
{
    __shared__ float smem[14336];  // tiles: kt[2][3072] vt[2][3072]; then combine
    const int tid  = threadIdx.x;
    const int lane = tid & 63;
    const int w    = __builtin_amdgcn_readfirstlane(tid >> 6);
    const int bb   = blockIdx.x >> 5;
    const int rg   = blockIdx.x & 31;
    const int row  = bb * 2048 + rg * 64 + lane;

    float q[12];
    {
        const float4* qp = (const float4*)(q_ws + (size_t)row * 12);
        float4 a = qp[0], b = qp[1], c = qp[2];
        q[0]=a.x; q[1]=a.y; q[2]=a.z;  q[3]=a.w;
        q[4]=b.x; q[5]=b.y; q[6]=b.z;  q[7]=b.w;
        q[8]=c.x; q[9]=c.y; q[10]=c.z; q[11]=c.w;
    }

    const float* kb = kc + (size_t)bb * 24576;
    const float* vb = vc + (size_t)bb * 24576;
    const int nv    = nvalid_arr[bb];
    const int ntile = (nv + 255) >> 8;

    // stage tile 0
    #pragma unroll
    for (int j = 0; j < 3; ++j) {
        int idx = tid + j * 1024;
        smem[idx]        = kb[idx];
        smem[6144 + idx] = vb[idx];
    }
    __syncthreads();

    float m = -INFINITY, l = 0.f;
    float o[12];
    #pragma unroll
    for (int j = 0; j < 12; ++j) o[j] = 0.f;
    const int k0 = w * 16;

    for (int t = 0; t < ntile; ++t) {
        const int cur = t & 1;
        const float* kt = smem + cur * 3072;
        const float* vt = smem + 6144 + cur * 3072;

        float pk[3], pv[3];
        const bool havenext = (t + 1 < ntile);
        if (havenext) {
            const int off = (t + 1) * 3072;
            #pragma unroll
            for (int j = 0; j < 3; ++j) {
                pk[j] = kb[off + tid + j * 1024];
                pv[j] = vb[off + tid + j * 1024];
            }
        }

        const int kbase = t * 256 + k0;
        float s[16];
        float mnew = m;
        #pragma unroll
        for (int i = 0; i < 16; ++i) {
            const float4* kr = (const float4*)(kt + (k0 + i) * 12);
            float4 a = kr[0], b = kr[1], c = kr[2];
            float t0 = q[0] * a.x, t1 = q[1] * a.y, t2 = q[2] * a.z, t3 = q[3] * a.w;
            t0 = fmaf(q[4], b.x, t0); t1 = fmaf(q[5], b.y, t1);
            t2 = fmaf(q[6], b.z, t2); t3 = fmaf(q[7], b.w, t3);
            t0 = fmaf(q[8], c.x, t0); t1 = fmaf(q[9], c.y, t1);
            t2 = fmaf(q[10], c.z, t2); t3 = fmaf(q[11], c.w, t3);
            float sv = (t0 + t1) + (t2 + t3);
            s[i] = (kbase + i < nv) ? sv : -INFINITY;
            mnew = fmaxf(mnew, s[i]);
        }
        float corr = (m < mnew) ? EXP2F(m - mnew) : 1.0f;
        l *= corr;
        #pragma unroll
        for (int j = 0; j < 12; ++j) o[j] *= corr;
        if (mnew > -INFINITY) {   // wave-uniform
            #pragma unroll
            for (int i = 0; i < 16; ++i) {
                float p = EXP2F(s[i] - mnew);
                l += p;
                const float4* vr = (const float4*)(vt + (k0 + i) * 12);
                float4 a = vr[0], b = vr[1], c = vr[2];
                o[0] = fmaf(p, a.x, o[0]);  o[1] = fmaf(p, a.y, o[1]);
                o[2] = fmaf(p, a.z, o[2]);  o[3] = fmaf(p, a.w, o[3]);
                o[4] = fmaf(p, b.x, o[4]);  o[5] = fmaf(p, b.y, o[5]);
                o[6] = fmaf(p, b.z, o[6]);  o[7] = fmaf(p, b.w, o[7]);
                o[8] = fmaf(p, c.x, o[8]);  o[9] = fmaf(p, c.y, o[9]);
                o[10] = fmaf(p, c.z, o[10]); o[11] = fmaf(p, c.w, o[11]);
            }
        }
        m = mnew;
        __syncthreads();   // everyone done with buffer (t+1)&1's old contents
        if (havenext) {
            const int nb = (t + 1) & 1;
            float* ktn = smem + nb * 3072;
            float* vtn = smem + 6144 + nb * 3072;
            #pragma unroll
            for (int j = 0; j < 3; ++j) {
                ktn[tid + j * 1024] = pk[j];
                vtn[tid + j * 1024] = pv[j];
            }
        }
        __syncthreads();
    }

    // ---- 16-way combine (aliases tile region; all compute done) ----
    float* cm = smem;          // 16*64
    float* cl = smem + 1024;   // 16*64
    float* co = smem + 2048;   // 16*64*12
    cm[w * 64 + lane] = m;
    cl[w * 64 + lane] = l;
    {
        float* p = co + (w * 64 + lane) * 12;
        #pragma unroll
        for (int j = 0; j < 12; ++j) p[j] = o[j];
    }
    __syncthreads();
    if (tid < 64) {
        float gm = -INFINITY;
        #pragma unroll
        for (int w2 = 0; w2 < 16; ++w2) gm = fmaxf(gm, cm[w2 * 64 + tid]);
        float L = 0.f;
        float O[12];
        #pragma unroll
        for (int j = 0; j < 12; ++j) O[j] = 0.f;
        #pragma unroll
        for (int w2 = 0; w2 < 16; ++w2) {
            float a = EXP2F(cm[w2 * 64 + tid] - gm);
            L = fmaf(cl[w2 * 64 + tid], a, L);
            const float* p = co + (w2 * 64 + tid) * 12;
            #pragma unroll
            for (int j = 0; j < 12; ++j) O[j] = fmaf(p[j], a, O[j]);
        }
        const float inv = 1.f / L;
        float4* op = (float4*)(out + (size_t)(bb * 2048 + rg * 64 + tid) * 12);
        op[0] = make_float4(O[0] * inv, O[1] * inv, O[2]  * inv, O[3]  * inv);
        op[1] = make_float4(O[4] * inv, O[5] * inv, O[6]  * inv, O[7]  * inv);
        op[2] = make_float4(O[8] * inv, O[9] * inv, O[10] * inv, O[11] * inv);
    }
}

extern "C" void kernel_launch(void* const* d_in, const int* in_sizes, int n_in,
                              void* d_out, int out_size, void* d_ws, size_t ws_size,
                              hipStream_t stream) {
    const float* x    = (const float*)d_in[0];
    const int*   mask = (const int*)  d_in[1];
    const float* Wk   = (const float*)d_in[2];   // key_weight
    const float* Wq   = (const float*)d_in[3];   // query_weight
    const float* Wv   = (const float*)d_in[4];   // value_weight
    float* out = (float*)d_out;

    float* ws     = (float*)d_ws;
    float* q_ws   = ws;                       // 16384*12
    float* kc     = ws + 196608;              // 8*2048*12 (compacted)
    float* vc     = ws + 393216;              // 8*2048*12 (compacted)
    int*   dst    = (int*)(ws + 589824);      // 16384
    int*   nvalid = (int*)(ws + 589824 + 16384);  // 8

    mask_scan<<<8, 256, 0, stream>>>(mask, dst, nvalid);
    qkv_proj<<<256, 512, 0, stream>>>(x, Wq, Wk, Wv, dst, q_ws, kc, vc);
    attn<<<256, 1024, 0, stream>>>(q_ws, kc, vc, nvalid, out);
}